// Round 6
// baseline (359.852 us; speedup 1.0000x reference)
//
#include <hip/hip_runtime.h>

// ---------------------------------------------------------------------------
// PhysNet stack, MI355X.
//   proto[i] = h_self[i] + fmtab[i] * (S[i] @ W_gate),  S module-invariant.
// ONE fused chain kernel (80 GEMM stages, 16 waves/block), weights DMA'd via
// global_load_lds (swizzled), all LDS addresses precomputed per-wave.
// S via LDS-histogram sort (LDS-tiled column scan) + predicated gather.
// ---------------------------------------------------------------------------

#define LN2F 0.69314718055994530942f
#define NB 64   // sort blocks

using short8  = __attribute__((ext_vector_type(8))) short;
using float4v = __attribute__((ext_vector_type(4))) float;
typedef const __attribute__((address_space(1))) unsigned int* gas1_t;
typedef __attribute__((address_space(3))) unsigned int* las3_t;

__device__ __forceinline__ float sspf(float x) {
  float ax = fabsf(x);
  return fmaxf(x, 0.0f) + __logf(1.0f + __expf(-ax)) - LN2F;
}

__device__ __forceinline__ unsigned short f2bf(float x) {
  return (unsigned short)((__float_as_uint(x) + 0x8000u) >> 16);  // RTN, <=0.5ulp
}

__device__ __forceinline__ unsigned short f2bf_ne(float x) {  // RTNE for weight prep
  unsigned int u = __float_as_uint(x);
  u += 0x7fffu + ((u >> 16) & 1u);
  return (unsigned short)(u >> 16);
}

__device__ __forceinline__ void dma16(const void* g, void* l) {
  __builtin_amdgcn_global_load_lds((gas1_t)(unsigned long long)g,
                                   (las3_t)(unsigned long long)l, 16, 0, 0);
}

// 16-wave block DMA: 32KB -> 2KB/wave, 16KB -> 1KB/wave
__device__ __forceinline__ void dma32k(const unsigned short* g, unsigned short* l,
                                       int w, int lane) {
  const char* gb = (const char*)g + w * 2048 + lane * 16;
  char* lb = (char*)l + w * 2048;
  dma16(gb, lb);
  dma16(gb + 1024, lb + 1024);
}
__device__ __forceinline__ void dma16k(const unsigned short* g, unsigned short* l,
                                       int w, int lane) {
  dma16((const char*)g + w * 1024 + lane * 16, (char*)l + w * 1024);
}

// ---------------------------------------------------------------------------
// S-path: LDS-hist sort + gather
// ---------------------------------------------------------------------------
__global__ __launch_bounds__(256) void hist_pass(const int* __restrict__ idx,
                                                 unsigned int* __restrict__ H,
                                                 int n2p, int C) {
  __shared__ unsigned int h[8192];
  int b = blockIdx.x, tid = threadIdx.x;
  for (int i = tid; i < 8192; i += 256) h[i] = 0;
  __syncthreads();
  int s = b * C, e = min(s + C, n2p);
  for (int i = s + tid; i < e; i += 256) atomicAdd(&h[idx[i]], 1u);
  __syncthreads();
  for (int i = tid; i < 8192; i += 256) H[(size_t)b * 8192 + i] = h[i];
}

// LDS-tiled per-bin exclusive scan over blocks + column totals
__global__ __launch_bounds__(256) void col_scan(unsigned int* __restrict__ H,
                                                unsigned int* __restrict__ tot) {
  __shared__ unsigned int h[NB * 256];   // 64 KB
  int t = threadIdx.x;
  size_t cb = (size_t)blockIdx.x * 256;
#pragma unroll 4
  for (int b = 0; b < NB; ++b) h[b * 256 + t] = H[(size_t)b * 8192 + cb + t];
  __syncthreads();
  unsigned int run = 0;
#pragma unroll
  for (int b = 0; b < NB; ++b) {
    unsigned int v = h[b * 256 + t];
    h[b * 256 + t] = run;
    run += v;
  }
  __syncthreads();
#pragma unroll 4
  for (int b = 0; b < NB; ++b) H[(size_t)b * 8192 + cb + t] = h[b * 256 + t];
  tot[cb + t] = run;
}

__global__ __launch_bounds__(256) void scan_kernel(const unsigned int* __restrict__ cnt,
                                                   unsigned int* __restrict__ off, int NA) {
  int t = threadIdx.x;
  unsigned int local[32], s = 0;
#pragma unroll
  for (int i = 0; i < 32; ++i) { local[i] = cnt[t * 32 + i]; s += local[i]; }
  unsigned int v = s;
  int lane = t & 63, w = t >> 6;
#pragma unroll
  for (int o = 1; o < 64; o <<= 1) {
    unsigned int u = __shfl_up(v, o, 64);
    if (lane >= o) v += u;
  }
  __shared__ unsigned int wt4[4];
  if (lane == 63) wt4[w] = v;
  __syncthreads();
  unsigned int base = 0;
  for (int k = 0; k < w; ++k) base += wt4[k];
  unsigned int excl = base + v - s;
#pragma unroll
  for (int i = 0; i < 32; ++i) { off[t * 32 + i] = excl; excl += local[i]; }
  if (t == 255) off[NA] = excl;
}

__global__ __launch_bounds__(256) void place_pass(const int* __restrict__ idx,
                                                  const unsigned int* __restrict__ H,
                                                  const unsigned int* __restrict__ off,
                                                  unsigned int* __restrict__ pairid,
                                                  int P, int C) {
  __shared__ unsigned int pos[8192];
  int b = blockIdx.x, tid = threadIdx.x;
  for (int i = tid; i < 8192; i += 256)
    pos[i] = off[i] + H[(size_t)b * 8192 + i];
  __syncthreads();
  int n2p = 2 * P;
  int s = b * C, e = min(s + C, n2p);
  for (int i = s + tid; i < e; i += 256) {
    int a = idx[i];
    unsigned int p = atomicAdd(&pos[a], 1u);
    pairid[p] = (i >= P) ? (unsigned int)(i - P) : (unsigned int)i;
  }
}

// fully-predicated 8-deep gather
__global__ __launch_bounds__(256) void gather_kernel(const float* __restrict__ radial,
                                                     const unsigned int* __restrict__ off,
                                                     const unsigned int* __restrict__ pairid,
                                                     float* __restrict__ S) {
  __shared__ float red[3][64];
  int a = blockIdx.x;
  int lane = threadIdx.x & 63, w = threadIdx.x >> 6;
  unsigned int b = off[a], e = off[a + 1];
  float acc = 0.0f;
  for (unsigned int base = b + w; base < e; base += 32) {
    unsigned int pp[8];
    float vv[8];
#pragma unroll
    for (int k = 0; k < 8; ++k) {
      unsigned int j = base + 4 * k;
      pp[k] = pairid[j < e ? j : b];
    }
#pragma unroll
    for (int k = 0; k < 8; ++k) vv[k] = radial[(size_t)pp[k] * 64 + lane];
#pragma unroll
    for (int k = 0; k < 8; ++k) {
      unsigned int j = base + 4 * k;
      acc += (j < e) ? vv[k] : 0.0f;
    }
  }
  if (w > 0) red[w - 1][lane] = acc;
  __syncthreads();
  if (w == 0) {
    acc += red[0][lane] + red[1][lane] + red[2][lane];
    S[(size_t)a * 64 + lane] = acc;
  }
}

// ---------------------------------------------------------------------------
// Fused prep: blocks 0..159 transpose+swizzle weights (2 blocks/matrix),
// blocks 160..164 pack biases.
// chunk(n,j) at pos = n*16 + (j^(n&15))  (gate: n*8 + (j^(n&7)))
// ---------------------------------------------------------------------------
struct PrepAll {
  const float* src[80];
  int isgate[80];
  const float* bp[17];
  int stride[17];
  const float* b_out;
};

__global__ __launch_bounds__(256) void prep_all(PrepAll A, unsigned short* __restrict__ Wt,
                                                float* __restrict__ bias_pack) {
  int bid = blockIdx.x;
  if (bid >= 160) {
    int l = bid - 160;
    for (int i = threadIdx.x; i < 17 * 128; i += 256) {
      int s = i >> 7;
      bias_pack[(size_t)l * 2304 + i] = A.bp[s][l * A.stride[s] + (i & 127)];
    }
    if (threadIdx.x == 0) bias_pack[(size_t)l * 2304 + 17 * 128] = A.b_out[l];
    return;
  }
  int m = bid >> 1, half = bid & 1;
  const float* s = A.src[m];
  unsigned short* d = Wt + (size_t)m * 16384;
  if (!A.isgate[m]) {
    for (int it = half * 4; it < half * 4 + 4; ++it) {
      int q = threadIdx.x + it * 256;
      int n = q & 127, j = q >> 7;
      unsigned short tmp[8];
#pragma unroll
      for (int cc = 0; cc < 8; ++cc) tmp[cc] = f2bf_ne(s[(8 * j + cc) * 128 + n]);
      *(uint4*)(d + (n * 16 + (j ^ (n & 15))) * 8) = *(uint4*)tmp;
    }
  } else {
    for (int it = half * 2; it < half * 2 + 2; ++it) {
      int q = threadIdx.x + it * 256;
      int n = q & 127, j = q >> 7;
      unsigned short tmp[8];
#pragma unroll
      for (int cc = 0; cc < 8; ++cc) tmp[cc] = f2bf_ne(s[(8 * j + cc) * 128 + n]);
      *(uint4*)(d + (n * 8 + (j ^ (n & 7))) * 8) = *(uint4*)tmp;
    }
  }
}

// ---------------------------------------------------------------------------
// Fused chain kernel: 1024 threads = 16 waves; wave (g,c): rows 16g..16g+15,
// cols 16c..16c+15. All LDS read/write offsets precomputed per-wave.
// ---------------------------------------------------------------------------
struct ChainArgs {
  const float* feat_in;
  const float* S;
  const unsigned short* wt;      // 80 slots x 16384 shorts
  const float* bias_pack;        // 5 x 2304 floats
  float* feat_out;
  float* energy;
};

#define MFMA16(a, b, acc) __builtin_amdgcn_mfma_f32_16x16x32_bf16(a, b, acc, 0, 0, 0)

__device__ __forceinline__ void gemm128o(const unsigned short* sAb, const unsigned short* swbb,
                                         unsigned as, unsigned ws,
                                         const unsigned aO[4], const unsigned bO[4],
                                         float4v* acc) {
  const char* ab = (const char*)sAb + as;
  const char* wb = (const char*)swbb + ws;
  short8 a0 = *(const short8*)(ab + aO[0]);
  short8 a1 = *(const short8*)(ab + aO[1]);
  short8 a2 = *(const short8*)(ab + aO[2]);
  short8 a3 = *(const short8*)(ab + aO[3]);
  *acc = MFMA16(a0, *(const short8*)(wb + bO[0]), *acc);
  *acc = MFMA16(a1, *(const short8*)(wb + bO[1]), *acc);
  *acc = MFMA16(a2, *(const short8*)(wb + bO[2]), *acc);
  *acc = MFMA16(a3, *(const short8*)(wb + bO[3]), *acc);
}

__device__ __forceinline__ void gemm64o(const unsigned short* sSb, const unsigned short* swbb,
                                        unsigned s0, unsigned s1, unsigned g0, unsigned g1,
                                        float4v* acc) {
  short8 a0 = *(const short8*)((const char*)sSb + s0);
  short8 a1 = *(const short8*)((const char*)sSb + s1);
  *acc = MFMA16(a0, *(const short8*)((const char*)swbb + g0), *acc);
  *acc = MFMA16(a1, *(const short8*)((const char*)swbb + g1), *acc);
}

__device__ __forceinline__ void wsspo(unsigned short* sAb, unsigned as,
                                      const unsigned wO[4], const float4v v) {
#pragma unroll
  for (int r = 0; r < 4; ++r)
    *(unsigned short*)((char*)sAb + as + wO[r]) = f2bf(sspf(v[r]));
}

__global__ __launch_bounds__(1024, 4) void chain_kernel(ChainArgs A) {
  __shared__ __align__(16) unsigned short swb[2 * 16384];   // 64 KB weight dbuf (flat)
  __shared__ __align__(16) unsigned short sA[2 * 32 * 136]; // act ping-pong (flat, 8704 B each)
  __shared__ __align__(16) unsigned short sS[32 * 72];
  __shared__ float sBias[2304];
  __shared__ float sE[32];

  const int tid  = threadIdx.x;
  const int row0 = blockIdx.x * 32;
  const int lane = tid & 63;
  const int w    = tid >> 6;       // 0..15
  const int g    = w >> 3;         // row group 0..1
  const int c    = w & 7;          // col 16-chunk 0..7
  const int l16  = lane & 15;
  const int quad = lane >> 4;
  const int arow = 16 * g;
  const int col0 = 16 * c + l16;
  const int l8   = l16 & 7;

  // ---- precomputed LDS byte offsets (loop-invariant; buffer select = literal)
  unsigned aO[4], bO[4], wO[4];
#pragma unroll
  for (int k = 0; k < 4; ++k) {
    aO[k] = (unsigned)(((arow + l16) * 136 + quad * 8 + k * 32) * 2);
    bO[k] = (unsigned)((col0 * 128 + ((quad + 4 * k) ^ l16) * 8) * 2);
    wO[k] = (unsigned)(((arow + quad * 4 + k) * 136 + col0) * 2);
  }
  const unsigned sO0 = (unsigned)(((arow + l16) * 72 + quad * 8) * 2);
  const unsigned sO1 = sO0 + 64;
  const unsigned gO0 = (unsigned)((col0 * 64 + ((quad + 0) ^ l8) * 8) * 2);
  const unsigned gO1 = (unsigned)((col0 * 64 + ((quad + 4) ^ l8) * 8) * 2);

  dma16k(A.wt, swb, w, lane);   // module-0 gate -> swb[0]

  for (int i = tid; i < 32 * 64; i += 1024) {
    int r = i >> 6, k = i & 63;
    sS[r * 72 + k] = f2bf(A.S[(size_t)(row0 + r) * 64 + k]);
  }
  for (int i = tid; i < 32 * 128; i += 1024) {
    int r = i >> 7, k = i & 127;
    sA[r * 136 + k] = f2bf(sspf(A.feat_in[(size_t)(row0 + r) * 128 + k]));
  }
  float4v ff;
#pragma unroll
  for (int r = 0; r < 4; ++r)
    ff[r] = A.feat_in[(size_t)(row0 + arow + quad * 4 + r) * 128 + col0];
  if (tid < 32) sE[tid] = 0.0f;
  __syncthreads();

  const float4v Z = {0.f, 0.f, 0.f, 0.f};
  float4v gG, fm, xf, t4;
  float p0 = 0.f, p1 = 0.f, p2 = 0.f, p3 = 0.f, bsum = 0.f;

#pragma unroll 1
  for (int l = 0; l < 5; ++l) {
    const size_t slot0 = (size_t)l * 16 * 16384;

    // ---- t=0: gate GEMM (swb+0); DMA W_J -> swb[1]; stage biases
    dma32k(A.wt + slot0 + 16384, swb + 16384, w, lane);
    for (int i = tid; i < 2304; i += 1024) sBias[i] = A.bias_pack[(size_t)l * 2304 + i];
    gG = Z;
    gemm64o(sS, swb, sO0, sO1, gO0, gO1, &gG);
    __syncthreads();

    // ---- t=1: W_J (sA0, swb1) -> fm ; DMA -> swb0
    dma32k(A.wt + slot0 + 2 * 16384, swb, w, lane);
    fm = Z;
    gemm128o(sA, swb, 0, 32768, aO, bO, &fm);
    {
      float bv = sBias[0 * 128 + col0];
#pragma unroll
      for (int r = 0; r < 4; ++r) fm[r] = sspf(fm[r] + bv);
    }
    __syncthreads();

    // ---- t=2: W_I (sA0, swb0); proto -> sA1 ; DMA -> swb1
    dma32k(A.wt + slot0 + 3 * 16384, swb + 16384, w, lane);
    t4 = Z;
    gemm128o(sA, swb, 0, 0, aO, bO, &t4);
    {
      float bv = sBias[1 * 128 + col0];
#pragma unroll
      for (int r = 0; r < 4; ++r) xf[r] = fm[r] * gG[r] + sspf(t4[r] + bv);
    }
    wsspo(sA, 8704, wO, xf);
    __syncthreads();

    // ---- t=3..8: ri chain x3
#pragma unroll
    for (int jj = 0; jj < 3; ++jj) {
      const int th = 3 + 2 * jj;   // odd: read sA1/swb1, write sA0, DMA->swb0
      dma32k(A.wt + slot0 + (size_t)(th + 1) * 16384, swb, w, lane);
      t4 = Z;
      gemm128o(sA, swb, 8704, 32768, aO, bO, &t4);
      {
        float bv = sBias[(th - 1) * 128 + col0];
#pragma unroll
        for (int r = 0; r < 4; ++r) t4[r] += bv;
      }
      wsspo(sA, 0, wO, t4);
      __syncthreads();

      const int tx = th + 1;       // even: read sA0/swb0, write sA1, DMA->swb1
      dma32k(A.wt + slot0 + (size_t)(tx + 1) * 16384, swb + 16384, w, lane);
      t4 = Z;
      gemm128o(sA, swb, 0, 0, aO, bO, &t4);
      {
        float bv = sBias[(tx - 1) * 128 + col0];
#pragma unroll
        for (int r = 0; r < 4; ++r) xf[r] += t4[r] + bv;
      }
      wsspo(sA, 8704, wO, xf);
      __syncthreads();
    }

    // ---- t=9: W_int (sA1, swb1): xf = ff*gvec + t4 + b -> sA0 ; DMA -> swb0
    dma32k(A.wt + slot0 + 10 * 16384, swb, w, lane);
    t4 = Z;
    gemm128o(sA, swb, 8704, 32768, aO, bO, &t4);
    {
      float bv = sBias[8 * 128 + col0];
      float gv = sBias[15 * 128 + col0];
#pragma unroll
      for (int r = 0; r < 4; ++r) xf[r] = ff[r] * gv + t4[r] + bv;
    }
    wsspo(sA, 0, wO, xf);
    __syncthreads();

    // ---- t=10..13: ra chain x2
#pragma unroll
    for (int jj = 0; jj < 2; ++jj) {
      const int th = 10 + 2 * jj;  // even: read sA0/swb0, write sA1, DMA->swb1
      dma32k(A.wt + slot0 + (size_t)(th + 1) * 16384, swb + 16384, w, lane);
      t4 = Z;
      gemm128o(sA, swb, 0, 0, aO, bO, &t4);
      {
        float bv = sBias[(th - 1) * 128 + col0];
#pragma unroll
        for (int r = 0; r < 4; ++r) t4[r] += bv;
      }
      wsspo(sA, 8704, wO, t4);
      __syncthreads();

      const int tx = th + 1;       // odd: read sA1/swb1, write sA0, DMA->swb0
      dma32k(A.wt + slot0 + (size_t)(tx + 1) * 16384, swb, w, lane);
      t4 = Z;
      gemm128o(sA, swb, 8704, 32768, aO, bO, &t4);
      {
        float bv = sBias[(tx - 1) * 128 + col0];
#pragma unroll
        for (int r = 0; r < 4; ++r) xf[r] += t4[r] + bv;
      }
      wsspo(sA, 0, wO, xf);
      __syncthreads();
    }

    // xf is feat2
    ff = xf;
    if (l == 4) {
#pragma unroll
      for (int r = 0; r < 4; ++r)
        A.feat_out[(size_t)(row0 + arow + quad * 4 + r) * 128 + col0] = xf[r];
    }

    // ---- t=14: ro_W1 (sA0, swb0) -> sA1 ; DMA -> swb1
    dma32k(A.wt + slot0 + 15 * 16384, swb + 16384, w, lane);
    t4 = Z;
    gemm128o(sA, swb, 0, 0, aO, bO, &t4);
    {
      float bv = sBias[13 * 128 + col0];
#pragma unroll
      for (int r = 0; r < 4; ++r) t4[r] += bv;
    }
    wsspo(sA, 8704, wO, t4);
    __syncthreads();

    // ---- t=15: ro_W2 (sA1, swb1); energy; DMA next gate -> swb0
    if (l < 4) dma16k(A.wt + slot0 + 16 * 16384, swb, w, lane);
    t4 = Z;
    gemm128o(sA, swb, 8704, 32768, aO, bO, &t4);
    {
      float bv = sBias[14 * 128 + col0];
      float wv = sBias[16 * 128 + col0];
      p0 += sspf(xf[0] + t4[0] + bv) * wv;
      p1 += sspf(xf[1] + t4[1] + bv) * wv;
      p2 += sspf(xf[2] + t4[2] + bv) * wv;
      p3 += sspf(xf[3] + t4[3] + bv) * wv;
    }
    bsum += sBias[17 * 128];
    __syncthreads();
  }

  // ---- energy reduction
#pragma unroll
  for (int o = 1; o < 16; o <<= 1) {
    p0 += __shfl_xor(p0, o, 64);
    p1 += __shfl_xor(p1, o, 64);
    p2 += __shfl_xor(p2, o, 64);
    p3 += __shfl_xor(p3, o, 64);
  }
  if (l16 == 0) {
    atomicAdd(&sE[arow + quad * 4 + 0], p0);
    atomicAdd(&sE[arow + quad * 4 + 1], p1);
    atomicAdd(&sE[arow + quad * 4 + 2], p2);
    atomicAdd(&sE[arow + quad * 4 + 3], p3);
  }
  __syncthreads();
  if (tid < 32) A.energy[row0 + tid] = sE[tid] + bsum;
}

// ---------------------------------------------------------------------------
extern "C" void kernel_launch(void* const* d_in, const int* in_sizes, int n_in,
                              void* d_out, int out_size, void* d_ws, size_t ws_size,
                              hipStream_t stream) {
  const float* features = (const float*)d_in[1];
  const float* radial   = (const float*)d_in[2];
  const int*   idx12    = (const int*)  d_in[3];
  const float* W_I    = (const float*)d_in[4];
  const float* b_I    = (const float*)d_in[5];
  const float* W_J    = (const float*)d_in[6];
  const float* b_J    = (const float*)d_in[7];
  const float* W_gate = (const float*)d_in[8];
  const float* gvec   = (const float*)d_in[9];
  const float* W_int  = (const float*)d_in[10];
  const float* b_int  = (const float*)d_in[11];
  const float* ri_W1  = (const float*)d_in[12];
  const float* ri_b1  = (const float*)d_in[13];
  const float* ri_W2  = (const float*)d_in[14];
  const float* ri_b2  = (const float*)d_in[15];
  const float* ra_W1  = (const float*)d_in[16];
  const float* ra_b1  = (const float*)d_in[17];
  const float* ra_W2  = (const float*)d_in[18];
  const float* ra_b2  = (const float*)d_in[19];
  const float* ro_W1  = (const float*)d_in[20];
  const float* ro_b1  = (const float*)d_in[21];
  const float* ro_W2  = (const float*)d_in[22];
  const float* ro_b2  = (const float*)d_in[23];
  const float* W_out  = (const float*)d_in[24];
  const float* b_out  = (const float*)d_in[25];

  const int N = in_sizes[1] / 128;   // 8192
  const int P = in_sizes[3] / 2;     // 400000
  const int L = in_sizes[25];        // 5
  const int n2p = 2 * P;
  const int C = (n2p + NB - 1) / NB;

  // ws layout: S | bias_pack | Wt | H | tot | off | pairid  (~10 MB)
  float* S = (float*)d_ws;
  float* bias_pack = S + (size_t)N * 64;
  unsigned short* Wt = (unsigned short*)(bias_pack + 5 * 2304);
  unsigned int* H      = (unsigned int*)(Wt + (size_t)80 * 16384);
  unsigned int* tot    = H + (size_t)NB * 8192;
  unsigned int* off    = tot + N;
  unsigned int* pairid = off + N + 4;

  // ---- fused weight+bias prep (consumption order: gate,WJ,WI,ri*6,Wint,ra*4,ro*2)
  PrepAll pa;
  for (int l = 0; l < L; ++l) {
    const float* fx[16] = {
      W_gate + l * 8192,
      W_J + l * 16384, W_I + l * 16384,
      ri_W1 + (l * 3 + 0) * 16384, ri_W2 + (l * 3 + 0) * 16384,
      ri_W1 + (l * 3 + 1) * 16384, ri_W2 + (l * 3 + 1) * 16384,
      ri_W1 + (l * 3 + 2) * 16384, ri_W2 + (l * 3 + 2) * 16384,
      W_int + l * 16384,
      ra_W1 + (l * 2 + 0) * 16384, ra_W2 + (l * 2 + 0) * 16384,
      ra_W1 + (l * 2 + 1) * 16384, ra_W2 + (l * 2 + 1) * 16384,
      ro_W1 + l * 16384, ro_W2 + l * 16384 };
    for (int t = 0; t < 16; ++t) { pa.src[l * 16 + t] = fx[t]; pa.isgate[l * 16 + t] = (t == 0); }
  }
  const float* bp[17] = { b_J, b_I,
    ri_b1, ri_b2, ri_b1 + 128, ri_b2 + 128, ri_b1 + 256, ri_b2 + 256,
    b_int, ra_b1, ra_b2, ra_b1 + 128, ra_b2 + 128, ro_b1, ro_b2, gvec, W_out };
  int st[17] = {128,128, 384,384,384,384,384,384, 128, 256,256,256,256, 128,128,128,128};
  for (int q = 0; q < 17; ++q) { pa.bp[q] = bp[q]; pa.stride[q] = st[q]; }
  pa.b_out = b_out;
  prep_all<<<165, 256, 0, stream>>>(pa, Wt, bias_pack);

  // ---- S via LDS-hist sort + gather
  hist_pass<<<NB, 256, 0, stream>>>(idx12, H, n2p, C);
  col_scan<<<32, 256, 0, stream>>>(H, tot);
  scan_kernel<<<1, 256, 0, stream>>>(tot, off, N);
  place_pass<<<NB, 256, 0, stream>>>(idx12, H, off, pairid, P, C);
  gather_kernel<<<N, 256, 0, stream>>>(radial, off, pairid, S);

  // ---- fused 5-module chain
  ChainArgs ca;
  ca.feat_in   = features;
  ca.S         = S;
  ca.wt        = Wt;
  ca.bias_pack = bias_pack;
  ca.energy    = (float*)d_out;
  ca.feat_out  = (float*)d_out + N;
  chain_kernel<<<N / 32, 1024, 0, stream>>>(ca);
}